// Round 1
// baseline (883.346 us; speedup 1.0000x reference)
//
#include <hip/hip_runtime.h>

// GNN: fc1 -> GCNConv x2 -> mean-pool -> L2norm -> fc2
// N=100000 nodes, E=1.6M edges, F=H=128, O=64, G=1024 graphs.
// Strategy: CSR-by-dst built on device each call (histogram + scan + scatter),
// pull-based aggregation (wave per node, no float atomics on features),
// fp32 vector GEMMs with W^T staged for coalesced loads.

#define CHK 1024  // scan chunk size

__global__ __launch_bounds__(256) void k_transpose128(const float* __restrict__ W,
                                                      float* __restrict__ WT) {
  int t = blockIdx.x * 256 + threadIdx.x;  // 0..16383
  int o = t >> 7, k = t & 127;
  WT[k * 128 + o] = W[t];
}

__global__ __launch_bounds__(256) void k_hist(const int* __restrict__ dst,
                                              const float* __restrict__ w,
                                              int* __restrict__ cnt,
                                              float* __restrict__ degf, int E) {
  int e = blockIdx.x * 256 + threadIdx.x;
  if (e < E) {
    int d = dst[e];
    atomicAdd(&cnt[d], 1);
    atomicAdd(&degf[d], w[e]);
  }
}

__global__ __launch_bounds__(256) void k_dis(const float* __restrict__ degf,
                                             float* __restrict__ dis,
                                             float* __restrict__ inv, int N) {
  int n = blockIdx.x * 256 + threadIdx.x;
  if (n < N) {
    float deg = degf[n] + 1.0f;  // self-loop weight 1
    dis[n] = rsqrtf(deg);
    inv[n] = 1.0f / deg;
  }
}

__global__ __launch_bounds__(256) void k_scan_reduce(const int* __restrict__ cnt,
                                                     int* __restrict__ chunkSum, int N) {
  __shared__ int sd[256];
  int b = blockIdx.x, t = threadIdx.x;
  int base = b * CHK + t * 4;
  int s = 0;
#pragma unroll
  for (int i = 0; i < 4; i++)
    if (base + i < N) s += cnt[base + i];
  sd[t] = s;
  __syncthreads();
  for (int off = 128; off; off >>= 1) {
    if (t < off) sd[t] += sd[t + off];
    __syncthreads();
  }
  if (t == 0) chunkSum[b] = sd[0];
}

__global__ void k_scan_chunks(const int* __restrict__ chunkSum,
                              int* __restrict__ chunkOff, int NC) {
  if (threadIdx.x == 0 && blockIdx.x == 0) {
    int s = 0;
    for (int i = 0; i < NC; i++) {
      chunkOff[i] = s;
      s += chunkSum[i];
    }
  }
}

__global__ __launch_bounds__(256) void k_scan_final(const int* __restrict__ cnt,
                                                    const int* __restrict__ chunkOff,
                                                    int* __restrict__ rowptr,
                                                    int* __restrict__ cursor, int N, int E) {
  __shared__ int sd[256];
  int b = blockIdx.x, t = threadIdx.x;
  int base = b * CHK + t * 4;
  int v[4], loc[4];
#pragma unroll
  for (int i = 0; i < 4; i++) v[i] = (base + i < N) ? cnt[base + i] : 0;
  loc[0] = 0;
  loc[1] = v[0];
  loc[2] = v[0] + v[1];
  loc[3] = v[0] + v[1] + v[2];
  int tot = loc[3] + v[3];
  sd[t] = tot;
  __syncthreads();
  for (int off = 1; off < 256; off <<= 1) {
    int xv = (t >= off) ? sd[t - off] : 0;
    __syncthreads();
    sd[t] += xv;
    __syncthreads();
  }
  int tbase = (t ? sd[t - 1] : 0) + chunkOff[b];
#pragma unroll
  for (int i = 0; i < 4; i++) {
    if (base + i < N) {
      int r = tbase + loc[i];
      rowptr[base + i] = r;
      cursor[base + i] = r;
    }
  }
  if (b == 0 && t == 0) rowptr[N] = E;
}

__global__ __launch_bounds__(256) void k_scatter(const int* __restrict__ src,
                                                 const int* __restrict__ dst,
                                                 const float* __restrict__ w,
                                                 const float* __restrict__ dis,
                                                 int* __restrict__ cursor,
                                                 int* __restrict__ csr_src,
                                                 float* __restrict__ csr_c, int E) {
  int e = blockIdx.x * 256 + threadIdx.x;
  if (e < E) {
    int s = src[e], d = dst[e];
    float c = w[e] * dis[s] * dis[d];
    int p = atomicAdd(&cursor[d], 1);
    csr_src[p] = s;
    csr_c[p] = c;
  }
}

// C[n][o] = sum_k A[n][k] * W[o][k]  (WT[k][o] = W[o][k]); optional bias+PReLU.
// Assumes N % 32 == 0 (100000 = 3125*32).
__global__ __launch_bounds__(256) void k_gemm128(const float* __restrict__ A,
                                                 const float* __restrict__ WT,
                                                 float* __restrict__ C,
                                                 const float* __restrict__ bias,
                                                 const float* __restrict__ slope, int N) {
  __shared__ float xs[32 * 128];
  int t = threadIdx.x;
  size_t base = (size_t)blockIdx.x * 32;
  {
    const float4* s4 = (const float4*)(A + base * 128);
    float4* d4 = (float4*)xs;
#pragma unroll
    for (int i = 0; i < 4; i++) d4[t + 256 * i] = s4[t + 256 * i];
  }
  __syncthreads();
  int cg = (t & 31) * 4;   // col base (0..124)
  int ng = (t >> 5) * 4;   // node base within tile (0..28)
  float acc[4][4];
#pragma unroll
  for (int u = 0; u < 4; u++)
#pragma unroll
    for (int c = 0; c < 4; c++) acc[u][c] = 0.f;

#pragma unroll 2
  for (int k0 = 0; k0 < 128; k0 += 4) {
    float4 xq[4];
#pragma unroll
    for (int u = 0; u < 4; u++) xq[u] = *(const float4*)&xs[(ng + u) * 128 + k0];
#pragma unroll
    for (int j = 0; j < 4; j++) {
      float4 wt = *(const float4*)&WT[(k0 + j) * 128 + cg];
#pragma unroll
      for (int u = 0; u < 4; u++) {
        float xv = ((const float*)&xq[u])[j];
        acc[u][0] += xv * wt.x;
        acc[u][1] += xv * wt.y;
        acc[u][2] += xv * wt.z;
        acc[u][3] += xv * wt.w;
      }
    }
  }
  float a = slope ? *slope : 1.0f;
#pragma unroll
  for (int u = 0; u < 4; u++) {
    size_t n = base + ng + u;
    float4 o;
    o.x = acc[u][0]; o.y = acc[u][1]; o.z = acc[u][2]; o.w = acc[u][3];
    if (bias) {
      o.x += bias[cg]; o.y += bias[cg + 1]; o.z += bias[cg + 2]; o.w += bias[cg + 3];
    }
    if (slope) {
      o.x = o.x >= 0.f ? o.x : a * o.x;
      o.y = o.y >= 0.f ? o.y : a * o.y;
      o.z = o.z >= 0.f ? o.z : a * o.z;
      o.w = o.w >= 0.f ? o.w : a * o.w;
    }
    *(float4*)&C[n * 128 + cg] = o;
  }
}

// Pull aggregation: wave per dst node, float2 per lane.
// out[n] = prelu( sum_{p in row} hW[src[p]]*c[p] + hW[n]*inv[n] + bias, a )
__global__ __launch_bounds__(256) void k_agg(const float* __restrict__ hW,
                                             const int* __restrict__ rowptr,
                                             const int* __restrict__ csr_src,
                                             const float* __restrict__ csr_c,
                                             const float* __restrict__ inv,
                                             const float* __restrict__ bias,
                                             const float* __restrict__ slope,
                                             float* __restrict__ out, int N) {
  int wid = (blockIdx.x * 256 + threadIdx.x) >> 6;
  if (wid >= N) return;
  int l = threadIdx.x & 63;
  int r0 = rowptr[wid], r1 = rowptr[wid + 1];
  float iv = inv[wid];
  float2 acc = *(const float2*)&hW[(size_t)wid * 128 + l * 2];
  acc.x *= iv;
  acc.y *= iv;
  int p = r0;
  for (; p + 2 <= r1; p += 2) {
    int s0 = csr_src[p], s1 = csr_src[p + 1];
    float c0 = csr_c[p], c1 = csr_c[p + 1];
    float2 v0 = *(const float2*)&hW[(size_t)s0 * 128 + l * 2];
    float2 v1 = *(const float2*)&hW[(size_t)s1 * 128 + l * 2];
    acc.x += v0.x * c0 + v1.x * c1;
    acc.y += v0.y * c0 + v1.y * c1;
  }
  if (p < r1) {
    int s = csr_src[p];
    float c = csr_c[p];
    float2 v = *(const float2*)&hW[(size_t)s * 128 + l * 2];
    acc.x += v.x * c;
    acc.y += v.y * c;
  }
  float a = *slope;
  float2 b = *(const float2*)&bias[l * 2];
  acc.x += b.x;
  acc.y += b.y;
  acc.x = acc.x >= 0.f ? acc.x : a * acc.x;
  acc.y = acc.y >= 0.f ? acc.y : a * acc.y;
  *(float2*)&out[(size_t)wid * 128 + l * 2] = acc;
}

// Same as k_agg but fuses mean-pool accumulation instead of writing h3.
__global__ __launch_bounds__(256) void k_agg_pool(const float* __restrict__ hW,
                                                  const int* __restrict__ rowptr,
                                                  const int* __restrict__ csr_src,
                                                  const float* __restrict__ csr_c,
                                                  const float* __restrict__ inv,
                                                  const float* __restrict__ bias,
                                                  const float* __restrict__ slope,
                                                  const int* __restrict__ batch,
                                                  float* __restrict__ pool,
                                                  float* __restrict__ cntg, int N) {
  int wid = (blockIdx.x * 256 + threadIdx.x) >> 6;
  if (wid >= N) return;
  int l = threadIdx.x & 63;
  int r0 = rowptr[wid], r1 = rowptr[wid + 1];
  float iv = inv[wid];
  float2 acc = *(const float2*)&hW[(size_t)wid * 128 + l * 2];
  acc.x *= iv;
  acc.y *= iv;
  int p = r0;
  for (; p + 2 <= r1; p += 2) {
    int s0 = csr_src[p], s1 = csr_src[p + 1];
    float c0 = csr_c[p], c1 = csr_c[p + 1];
    float2 v0 = *(const float2*)&hW[(size_t)s0 * 128 + l * 2];
    float2 v1 = *(const float2*)&hW[(size_t)s1 * 128 + l * 2];
    acc.x += v0.x * c0 + v1.x * c1;
    acc.y += v0.y * c0 + v1.y * c1;
  }
  if (p < r1) {
    int s = csr_src[p];
    float c = csr_c[p];
    float2 v = *(const float2*)&hW[(size_t)s * 128 + l * 2];
    acc.x += v.x * c;
    acc.y += v.y * c;
  }
  float a = *slope;
  float2 b = *(const float2*)&bias[l * 2];
  acc.x += b.x;
  acc.y += b.y;
  acc.x = acc.x >= 0.f ? acc.x : a * acc.x;
  acc.y = acc.y >= 0.f ? acc.y : a * acc.y;
  int g = batch[wid];
  atomicAdd(&pool[(size_t)g * 128 + l * 2], acc.x);
  atomicAdd(&pool[(size_t)g * 128 + l * 2 + 1], acc.y);
  if (l == 0) atomicAdd(&cntg[g], 1.0f);
}

// Per-graph: mean, L2-normalize, out = hg @ fc2_w.T + fc2_b.  1 wave/graph.
__global__ __launch_bounds__(64) void k_final(const float* __restrict__ pool,
                                              const float* __restrict__ cntg,
                                              const float* __restrict__ fc2w,
                                              const float* __restrict__ fc2b,
                                              float* __restrict__ out) {
  __shared__ float hg[128];
  int g = blockIdx.x, l = threadIdx.x;
  float cnt = cntg[g];
  float ic = 1.0f / fmaxf(cnt, 1.0f);
  float2 v = *(const float2*)&pool[(size_t)g * 128 + l * 2];
  v.x *= ic;
  v.y *= ic;
  float ss = v.x * v.x + v.y * v.y;
#pragma unroll
  for (int off = 1; off < 64; off <<= 1) ss += __shfl_xor(ss, off);
  float nrm = sqrtf(ss);
  float sc = 1.0f / fmaxf(nrm, 1e-12f);
  hg[l * 2] = v.x * sc;
  hg[l * 2 + 1] = v.y * sc;
  __syncthreads();
  float acc = fc2b[l];
#pragma unroll 4
  for (int k = 0; k < 128; k++) acc += hg[k] * fc2w[l * 128 + k];
  out[(size_t)g * 64 + l] = acc;
}

extern "C" void kernel_launch(void* const* d_in, const int* in_sizes, int n_in,
                              void* d_out, int out_size, void* d_ws, size_t ws_size,
                              hipStream_t stream) {
  const float* x = (const float*)d_in[0];
  const int* ei = (const int*)d_in[1];
  const float* ew = (const float*)d_in[2];
  const int* batch = (const int*)d_in[3];
  const float* fc1_w = (const float*)d_in[4];
  const float* fc1_b = (const float*)d_in[5];
  const float* gc1_w = (const float*)d_in[6];
  const float* gc1_b = (const float*)d_in[7];
  const float* gc2_w = (const float*)d_in[8];
  const float* gc2_b = (const float*)d_in[9];
  const float* fc2_w = (const float*)d_in[10];
  const float* fc2_b = (const float*)d_in[11];
  const float* a_fc1 = (const float*)d_in[12];
  const float* a_gc1 = (const float*)d_in[13];
  const float* a_gc2 = (const float*)d_in[14];

  int N = in_sizes[0] / 128;
  int E = in_sizes[2];
  int G = out_size / 64;
  const int* src = ei;
  const int* dst = ei + E;

  char* p = (char*)d_ws;
  auto carve = [&](size_t bytes) -> char* {
    char* r = p;
    p += (bytes + 255) & ~(size_t)255;
    return r;
  };
  float* bufA = (float*)carve((size_t)N * 128 * 4);
  float* bufB = (float*)carve((size_t)N * 128 * 4);
  int* csr_src = (int*)carve((size_t)E * 4);
  float* csr_c = (float*)carve((size_t)E * 4);
  int* cnt = (int*)carve((size_t)N * 4);
  int* rowptr = (int*)carve((size_t)(N + 1) * 4);
  int* cursor = (int*)carve((size_t)N * 4);
  float* degf = (float*)carve((size_t)N * 4);
  float* dis = (float*)carve((size_t)N * 4);
  float* inv = (float*)carve((size_t)N * 4);
  float* WT1 = (float*)carve(16384 * 4);
  float* WT2 = (float*)carve(16384 * 4);
  float* WT3 = (float*)carve(16384 * 4);
  int NC = (N + CHK - 1) / CHK;
  int* chunkSum = (int*)carve((size_t)NC * 4);
  int* chunkOff = (int*)carve((size_t)NC * 4);
  float* pool = (float*)carve((size_t)G * 128 * 4);
  float* cntg = (float*)carve((size_t)G * 4);

  hipMemsetAsync(cnt, 0, (size_t)N * 4, stream);
  hipMemsetAsync(degf, 0, (size_t)N * 4, stream);
  hipMemsetAsync(pool, 0, (size_t)G * 128 * 4, stream);
  hipMemsetAsync(cntg, 0, (size_t)G * 4, stream);

  k_transpose128<<<64, 256, 0, stream>>>(fc1_w, WT1);
  k_transpose128<<<64, 256, 0, stream>>>(gc1_w, WT2);
  k_transpose128<<<64, 256, 0, stream>>>(gc2_w, WT3);

  int gE = (E + 255) / 256;
  int gN = (N + 255) / 256;
  k_hist<<<gE, 256, 0, stream>>>(dst, ew, cnt, degf, E);
  k_dis<<<gN, 256, 0, stream>>>(degf, dis, inv, N);
  k_scan_reduce<<<NC, 256, 0, stream>>>(cnt, chunkSum, N);
  k_scan_chunks<<<1, 64, 0, stream>>>(chunkSum, chunkOff, NC);
  k_scan_final<<<NC, 256, 0, stream>>>(cnt, chunkOff, rowptr, cursor, N, E);
  k_scatter<<<gE, 256, 0, stream>>>(src, dst, ew, dis, cursor, csr_src, csr_c, E);

  // h = prelu(x @ fc1_w.T + fc1_b)
  k_gemm128<<<N / 32, 256, 0, stream>>>(x, WT1, bufA, fc1_b, a_fc1, N);
  // conv1: hW = h @ gc1_w.T ; aggregate -> h (bufA)
  k_gemm128<<<N / 32, 256, 0, stream>>>(bufA, WT2, bufB, nullptr, nullptr, N);
  int gAgg = ((size_t)N * 64 + 255) / 256;
  k_agg<<<gAgg, 256, 0, stream>>>(bufB, rowptr, csr_src, csr_c, inv, gc1_b, a_gc1, bufA, N);
  // conv2: hW = h @ gc2_w.T ; aggregate + pool (fused)
  k_gemm128<<<N / 32, 256, 0, stream>>>(bufA, WT3, bufB, nullptr, nullptr, N);
  k_agg_pool<<<gAgg, 256, 0, stream>>>(bufB, rowptr, csr_src, csr_c, inv, gc2_b, a_gc2,
                                       batch, pool, cntg, N);
  k_final<<<G, 64, 0, stream>>>(pool, cntg, fc2_w, fc2_b, (float*)d_out);
}

// Round 2
// 743.852 us; speedup vs baseline: 1.1875x; 1.1875x over previous
//
#include <hip/hip_runtime.h>
#include <hip/hip_fp16.h>

// GNN: fc1 -> GCNConv x2 -> mean-pool -> L2norm -> fc2
// N=100000 nodes, E=1.6M edges, F=H=128, O=64, G=1024 graphs.
// R1: aggregation restructured for memory-level parallelism (8 gathers in
// flight, lane-parallel CSR prefetch + shfl broadcast) and fp16 hW gathers
// (half the bytes, fp32 accumulate).

#define CHK 1024  // scan chunk size

typedef unsigned int u32;

__global__ __launch_bounds__(256) void k_transpose128(const float* __restrict__ W,
                                                      float* __restrict__ WT) {
  int t = blockIdx.x * 256 + threadIdx.x;  // 0..16383
  int o = t >> 7, k = t & 127;
  WT[k * 128 + o] = W[t];
}

__global__ __launch_bounds__(256) void k_hist(const int* __restrict__ dst,
                                              const float* __restrict__ w,
                                              int* __restrict__ cnt,
                                              float* __restrict__ degf, int E) {
  int e = blockIdx.x * 256 + threadIdx.x;
  if (e < E) {
    int d = dst[e];
    atomicAdd(&cnt[d], 1);
    atomicAdd(&degf[d], w[e]);
  }
}

__global__ __launch_bounds__(256) void k_dis(const float* __restrict__ degf,
                                             float* __restrict__ dis,
                                             float* __restrict__ inv, int N) {
  int n = blockIdx.x * 256 + threadIdx.x;
  if (n < N) {
    float deg = degf[n] + 1.0f;  // self-loop weight 1
    dis[n] = rsqrtf(deg);
    inv[n] = 1.0f / deg;
  }
}

__global__ __launch_bounds__(256) void k_scan_reduce(const int* __restrict__ cnt,
                                                     int* __restrict__ chunkSum, int N) {
  __shared__ int sd[256];
  int b = blockIdx.x, t = threadIdx.x;
  int base = b * CHK + t * 4;
  int s = 0;
#pragma unroll
  for (int i = 0; i < 4; i++)
    if (base + i < N) s += cnt[base + i];
  sd[t] = s;
  __syncthreads();
  for (int off = 128; off; off >>= 1) {
    if (t < off) sd[t] += sd[t + off];
    __syncthreads();
  }
  if (t == 0) chunkSum[b] = sd[0];
}

__global__ void k_scan_chunks(const int* __restrict__ chunkSum,
                              int* __restrict__ chunkOff, int NC) {
  if (threadIdx.x == 0 && blockIdx.x == 0) {
    int s = 0;
    for (int i = 0; i < NC; i++) {
      chunkOff[i] = s;
      s += chunkSum[i];
    }
  }
}

__global__ __launch_bounds__(256) void k_scan_final(const int* __restrict__ cnt,
                                                    const int* __restrict__ chunkOff,
                                                    int* __restrict__ rowptr,
                                                    int* __restrict__ cursor, int N, int E) {
  __shared__ int sd[256];
  int b = blockIdx.x, t = threadIdx.x;
  int base = b * CHK + t * 4;
  int v[4], loc[4];
#pragma unroll
  for (int i = 0; i < 4; i++) v[i] = (base + i < N) ? cnt[base + i] : 0;
  loc[0] = 0;
  loc[1] = v[0];
  loc[2] = v[0] + v[1];
  loc[3] = v[0] + v[1] + v[2];
  int tot = loc[3] + v[3];
  sd[t] = tot;
  __syncthreads();
  for (int off = 1; off < 256; off <<= 1) {
    int xv = (t >= off) ? sd[t - off] : 0;
    __syncthreads();
    sd[t] += xv;
    __syncthreads();
  }
  int tbase = (t ? sd[t - 1] : 0) + chunkOff[b];
#pragma unroll
  for (int i = 0; i < 4; i++) {
    if (base + i < N) {
      int r = tbase + loc[i];
      rowptr[base + i] = r;
      cursor[base + i] = r;
    }
  }
  if (b == 0 && t == 0) rowptr[N] = E;
}

__global__ __launch_bounds__(256) void k_scatter(const int* __restrict__ src,
                                                 const int* __restrict__ dst,
                                                 const float* __restrict__ w,
                                                 const float* __restrict__ dis,
                                                 int* __restrict__ cursor,
                                                 int* __restrict__ csr_src,
                                                 float* __restrict__ csr_c, int E) {
  int e = blockIdx.x * 256 + threadIdx.x;
  if (e < E) {
    int s = src[e], d = dst[e];
    float c = w[e] * dis[s] * dis[d];
    int p = atomicAdd(&cursor[d], 1);
    csr_src[p] = s;
    csr_c[p] = c;
  }
}

// C[n][o] = sum_k A[n][k] * W[o][k]  (WT[k][o] = W[o][k]); optional bias+PReLU.
// HALF_OUT: write fp16 (half2-packed) instead of fp32.
template <bool HALF_OUT>
__global__ __launch_bounds__(256) void k_gemm128(const float* __restrict__ A,
                                                 const float* __restrict__ WT,
                                                 float* __restrict__ C,
                                                 __half2* __restrict__ Ch,
                                                 const float* __restrict__ bias,
                                                 const float* __restrict__ slope, int N) {
  __shared__ float xs[32 * 128];
  int t = threadIdx.x;
  size_t base = (size_t)blockIdx.x * 32;
  {
    const float4* s4 = (const float4*)(A + base * 128);
    float4* d4 = (float4*)xs;
#pragma unroll
    for (int i = 0; i < 4; i++) d4[t + 256 * i] = s4[t + 256 * i];
  }
  __syncthreads();
  int cg = (t & 31) * 4;   // col base (0..124)
  int ng = (t >> 5) * 4;   // node base within tile (0..28)
  float acc[4][4];
#pragma unroll
  for (int u = 0; u < 4; u++)
#pragma unroll
    for (int c = 0; c < 4; c++) acc[u][c] = 0.f;

#pragma unroll 2
  for (int k0 = 0; k0 < 128; k0 += 4) {
    float4 xq[4];
#pragma unroll
    for (int u = 0; u < 4; u++) xq[u] = *(const float4*)&xs[(ng + u) * 128 + k0];
#pragma unroll
    for (int j = 0; j < 4; j++) {
      float4 wt = *(const float4*)&WT[(k0 + j) * 128 + cg];
#pragma unroll
      for (int u = 0; u < 4; u++) {
        float xv = ((const float*)&xq[u])[j];
        acc[u][0] += xv * wt.x;
        acc[u][1] += xv * wt.y;
        acc[u][2] += xv * wt.z;
        acc[u][3] += xv * wt.w;
      }
    }
  }
  float a = slope ? *slope : 1.0f;
#pragma unroll
  for (int u = 0; u < 4; u++) {
    size_t n = base + ng + u;
    float4 o;
    o.x = acc[u][0]; o.y = acc[u][1]; o.z = acc[u][2]; o.w = acc[u][3];
    if (bias) {
      o.x += bias[cg]; o.y += bias[cg + 1]; o.z += bias[cg + 2]; o.w += bias[cg + 3];
    }
    if (slope) {
      o.x = o.x >= 0.f ? o.x : a * o.x;
      o.y = o.y >= 0.f ? o.y : a * o.y;
      o.z = o.z >= 0.f ? o.z : a * o.z;
      o.w = o.w >= 0.f ? o.w : a * o.w;
    }
    if (HALF_OUT) {
      __half2 h0 = __float22half2_rn(make_float2(o.x, o.y));
      __half2 h1 = __float22half2_rn(make_float2(o.z, o.w));
      __half2* dsth = &Ch[n * 64 + (cg >> 1)];
      dsth[0] = h0;
      dsth[1] = h1;
    } else {
      *(float4*)&C[n * 128 + cg] = o;
    }
  }
}

// Pull aggregation: wave per dst node; hW is fp16 (__half2, 64 per row);
// lane-parallel CSR prefetch + shfl broadcast; 8 gathers in flight.
// out[n] = prelu( sum_{p} hW[src[p]]*c[p] + hW[n]*inv[n] + bias, a )
// POOL: instead of writing out, atomically accumulate into pool[batch[n]].
template <bool POOL>
__global__ __launch_bounds__(256) void k_agg_h(const __half2* __restrict__ hW,
                                               const int* __restrict__ rowptr,
                                               const int* __restrict__ csr_src,
                                               const float* __restrict__ csr_c,
                                               const float* __restrict__ inv,
                                               const float* __restrict__ bias,
                                               const float* __restrict__ slope,
                                               const int* __restrict__ batch,
                                               float* __restrict__ out,
                                               float* __restrict__ cntg, int N) {
  int wid = (blockIdx.x * 256 + threadIdx.x) >> 6;
  if (wid >= N) return;
  int l = threadIdx.x & 63;
  int r0 = rowptr[wid], r1 = rowptr[wid + 1];
  float2 acc;
  {
    float2 f = __half22float2(hW[(size_t)wid * 64 + l]);
    float iv = inv[wid];
    acc.x = f.x * iv;
    acc.y = f.y * iv;
  }
  for (int base = r0; base < r1; base += 64) {
    int idx = base + l;
    int sl = 0;
    float cl = 0.f;
    if (idx < r1) {
      sl = csr_src[idx];
      cl = csr_c[idx];
    }
    int m = min(64, r1 - base);
    for (int k = 0; k < m; k += 8) {
      __half2 v[8];
      float c[8];
#pragma unroll
      for (int i = 0; i < 8; i++) {
        int s = __shfl(sl, k + i);
        c[i] = __shfl(cl, k + i);
        v[i] = hW[(size_t)s * 64 + l];  // OOB lanes: s=0,c=0 -> harmless hot line
      }
#pragma unroll
      for (int i = 0; i < 8; i++) {
        float2 f = __half22float2(v[i]);
        acc.x += f.x * c[i];
        acc.y += f.y * c[i];
      }
    }
  }
  float a = *slope;
  float2 b = *(const float2*)&bias[l * 2];
  acc.x += b.x;
  acc.y += b.y;
  acc.x = acc.x >= 0.f ? acc.x : a * acc.x;
  acc.y = acc.y >= 0.f ? acc.y : a * acc.y;
  if (POOL) {
    int g = batch[wid];
    atomicAdd(&out[(size_t)g * 128 + l * 2], acc.x);
    atomicAdd(&out[(size_t)g * 128 + l * 2 + 1], acc.y);
    if (l == 0) atomicAdd(&cntg[wid < N ? g : 0], 1.0f);
  } else {
    *(float2*)&out[(size_t)wid * 128 + l * 2] = acc;
  }
}

// Per-graph: mean, L2-normalize, out = hg @ fc2_w.T + fc2_b.  1 wave/graph.
__global__ __launch_bounds__(64) void k_final(const float* __restrict__ pool,
                                              const float* __restrict__ cntg,
                                              const float* __restrict__ fc2w,
                                              const float* __restrict__ fc2b,
                                              float* __restrict__ out) {
  __shared__ float hg[128];
  int g = blockIdx.x, l = threadIdx.x;
  float cnt = cntg[g];
  float ic = 1.0f / fmaxf(cnt, 1.0f);
  float2 v = *(const float2*)&pool[(size_t)g * 128 + l * 2];
  v.x *= ic;
  v.y *= ic;
  float ss = v.x * v.x + v.y * v.y;
#pragma unroll
  for (int off = 1; off < 64; off <<= 1) ss += __shfl_xor(ss, off);
  float nrm = sqrtf(ss);
  float sc = 1.0f / fmaxf(nrm, 1e-12f);
  hg[l * 2] = v.x * sc;
  hg[l * 2 + 1] = v.y * sc;
  __syncthreads();
  float acc = fc2b[l];
#pragma unroll 4
  for (int k = 0; k < 128; k++) acc += hg[k] * fc2w[l * 128 + k];
  out[(size_t)g * 64 + l] = acc;
}

extern "C" void kernel_launch(void* const* d_in, const int* in_sizes, int n_in,
                              void* d_out, int out_size, void* d_ws, size_t ws_size,
                              hipStream_t stream) {
  const float* x = (const float*)d_in[0];
  const int* ei = (const int*)d_in[1];
  const float* ew = (const float*)d_in[2];
  const int* batch = (const int*)d_in[3];
  const float* fc1_w = (const float*)d_in[4];
  const float* fc1_b = (const float*)d_in[5];
  const float* gc1_w = (const float*)d_in[6];
  const float* gc1_b = (const float*)d_in[7];
  const float* gc2_w = (const float*)d_in[8];
  const float* gc2_b = (const float*)d_in[9];
  const float* fc2_w = (const float*)d_in[10];
  const float* fc2_b = (const float*)d_in[11];
  const float* a_fc1 = (const float*)d_in[12];
  const float* a_gc1 = (const float*)d_in[13];
  const float* a_gc2 = (const float*)d_in[14];

  int N = in_sizes[0] / 128;
  int E = in_sizes[2];
  int G = out_size / 64;
  const int* src = ei;
  const int* dst = ei + E;

  char* p = (char*)d_ws;
  auto carve = [&](size_t bytes) -> char* {
    char* r = p;
    p += (bytes + 255) & ~(size_t)255;
    return r;
  };
  float* bufA = (float*)carve((size_t)N * 128 * 4);
  __half2* bufH = (__half2*)carve((size_t)N * 64 * 4);  // fp16 hW
  int* csr_src = (int*)carve((size_t)E * 4);
  float* csr_c = (float*)carve((size_t)E * 4);
  int* cnt = (int*)carve((size_t)N * 4);
  int* rowptr = (int*)carve((size_t)(N + 1) * 4);
  int* cursor = (int*)carve((size_t)N * 4);
  float* degf = (float*)carve((size_t)N * 4);
  float* dis = (float*)carve((size_t)N * 4);
  float* inv = (float*)carve((size_t)N * 4);
  float* WT1 = (float*)carve(16384 * 4);
  float* WT2 = (float*)carve(16384 * 4);
  float* WT3 = (float*)carve(16384 * 4);
  int NC = (N + CHK - 1) / CHK;
  int* chunkSum = (int*)carve((size_t)NC * 4);
  int* chunkOff = (int*)carve((size_t)NC * 4);
  float* pool = (float*)carve((size_t)G * 128 * 4);
  float* cntg = (float*)carve((size_t)G * 4);

  hipMemsetAsync(cnt, 0, (size_t)N * 4, stream);
  hipMemsetAsync(degf, 0, (size_t)N * 4, stream);
  hipMemsetAsync(pool, 0, (size_t)G * 128 * 4, stream);
  hipMemsetAsync(cntg, 0, (size_t)G * 4, stream);

  k_transpose128<<<64, 256, 0, stream>>>(fc1_w, WT1);
  k_transpose128<<<64, 256, 0, stream>>>(gc1_w, WT2);
  k_transpose128<<<64, 256, 0, stream>>>(gc2_w, WT3);

  int gE = (E + 255) / 256;
  int gN = (N + 255) / 256;
  k_hist<<<gE, 256, 0, stream>>>(dst, ew, cnt, degf, E);
  k_dis<<<gN, 256, 0, stream>>>(degf, dis, inv, N);
  k_scan_reduce<<<NC, 256, 0, stream>>>(cnt, chunkSum, N);
  k_scan_chunks<<<1, 64, 0, stream>>>(chunkSum, chunkOff, NC);
  k_scan_final<<<NC, 256, 0, stream>>>(cnt, chunkOff, rowptr, cursor, N, E);
  k_scatter<<<gE, 256, 0, stream>>>(src, dst, ew, dis, cursor, csr_src, csr_c, E);

  // h = prelu(x @ fc1_w.T + fc1_b)  -> bufA (fp32)
  k_gemm128<false><<<N / 32, 256, 0, stream>>>(x, WT1, bufA, nullptr, fc1_b, a_fc1, N);
  // conv1: hW = h @ gc1_w.T (fp16) ; aggregate -> bufA (fp32)
  k_gemm128<true><<<N / 32, 256, 0, stream>>>(bufA, WT2, nullptr, bufH, nullptr, nullptr, N);
  int gAgg = (int)(((size_t)N * 64 + 255) / 256);
  k_agg_h<false><<<gAgg, 256, 0, stream>>>(bufH, rowptr, csr_src, csr_c, inv, gc1_b, a_gc1,
                                           batch, bufA, cntg, N);
  // conv2: hW = h @ gc2_w.T (fp16) ; aggregate + pool (fused)
  k_gemm128<true><<<N / 32, 256, 0, stream>>>(bufA, WT3, nullptr, bufH, nullptr, nullptr, N);
  k_agg_h<true><<<gAgg, 256, 0, stream>>>(bufH, rowptr, csr_src, csr_c, inv, gc2_b, a_gc2,
                                          batch, pool, cntg, N);
  k_final<<<G, 64, 0, stream>>>(pool, cntg, fc2_w, fc2_b, (float*)d_out);
}